// Round 14
// baseline (246.618 us; speedup 1.0000x reference)
//
#include <hip/hip_runtime.h>
#include <math.h>

typedef __attribute__((ext_vector_type(4))) float  f32x4;
typedef __attribute__((ext_vector_type(8))) short  short8;
typedef __attribute__((ext_vector_type(8))) unsigned short usx8;

__device__ __forceinline__ unsigned short f2bf(float f) {
    union { float f; unsigned int i; } c; c.f = f;
    unsigned int x = c.i;
    unsigned int r = (x + 0x7FFFu + ((x >> 16) & 1u)) >> 16;  // round-nearest-even
    return (unsigned short)r;
}

// ---------------- fused prep: zero CSR counters + convert W + convert x ----------------
// block ranges: [0,nz) zero ints; [nz,nz+512) build wbt; [nz+512, +nx) x->bf16
__global__ __launch_bounds__(256) void k_prep(
    int* __restrict__ zr, int zn,
    const float* __restrict__ Wg, const float* __restrict__ Wf,
    unsigned short* __restrict__ wbt,
    const float* __restrict__ x, unsigned short* __restrict__ xb,
    long total8, int nz) {
    int b = blockIdx.x;
    if (b < nz) {
        int i = b * 256 + threadIdx.x;
        if (i < zn) zr[i] = 0;
        return;
    }
    b -= nz;
    if (b < 512) {
        int idx = b * 256 + threadIdx.x;
        int c = idx >> 8;
        int k = idx & 255;
        float v = (c < 256) ? Wg[k * 256 + c] : Wf[k * 256 + (c - 256)];
        wbt[idx] = f2bf(v);
        return;
    }
    b -= 512;
    long i = (long)b * 256 + threadIdx.x;
    if (i >= total8 || !xb) return;
    const f32x4* p = (const f32x4*)x;
    f32x4 v0 = p[2 * i], v1 = p[2 * i + 1];
    usx8 o;
    o[0] = f2bf(v0[0]); o[1] = f2bf(v0[1]); o[2] = f2bf(v0[2]); o[3] = f2bf(v0[3]);
    o[4] = f2bf(v1[0]); o[5] = f2bf(v1[1]); o[6] = f2bf(v1[2]); o[7] = f2bf(v1[3]);
    ((usx8*)xb)[i] = o;
}

#define BM 128
#define BN 128

// ------- fast GEMM: global_load_lds + BK=64 + XOR-swizzle + DOUBLE-BUFFERED LDS -------
// One __syncthreads per K-step: barrier ensures tile kk landed; then issue kk+1 into
// the other buffer; compute kk while those loads fly (drained at the NEXT barrier).
__global__ __launch_bounds__(256, 2) void k_gemm_fast(
    const unsigned short* __restrict__ xb,    // [M][256] bf16
    const unsigned short* __restrict__ wbt,   // [512][256] bf16
    unsigned short* __restrict__ hb,          // [M][256] bf16 (GAT h)
    unsigned short* __restrict__ tb,          // [M][256] bf16 transformed (or null)
    float* __restrict__ out,                  // fallback f32 transformed target
    const float* __restrict__ att_s, const float* __restrict__ att_d,
    float* __restrict__ a_src, float* __restrict__ a_dst,
    const float* __restrict__ b_ft, const float* __restrict__ bn_g,
    const float* __restrict__ bn_b, const float* __restrict__ bn_m,
    const float* __restrict__ bn_v, int M) {
    __shared__ unsigned short As[2][128 * 64];   // 2 x 16 KB
    __shared__ unsigned short Bs[2][128 * 64];   // 2 x 16 KB
    const int t = threadIdx.x;
    const int w = t >> 6, l = t & 63;
    const int wr = w >> 1, wc = w & 1;
    const int bm0 = blockIdx.y * BM;
    const int bn0 = blockIdx.x * BN;          // 0,128 -> h; 256,384 -> transformed
    const int kg = l >> 4;
    const int lm = l & 15;

    const int srow = l >> 3;                  // 0..7 within 8-row stripe
    const int scol = ((l & 7) ^ srow) << 3;   // pre-swizzled source col (bf16 units)

    // per-thread global row for staging (wave w stages rows w*32 .. w*32+31)
    int garow[4], gbrow[4];
#pragma unroll
    for (int j = 0; j < 4; j++) {
        int r = ((w * 4 + j) << 3) + srow;    // 0..127
        int ga = bm0 + r; if (ga >= M) ga = M - 1;
        garow[j] = ga;
        gbrow[j] = bn0 + r;
    }

#define ISSUE(kk, buf)                                                        \
    {                                                                         \
        const int k0_ = (kk) * 64;                                            \
        _Pragma("unroll")                                                     \
        for (int j = 0; j < 4; j++) {                                         \
            __builtin_amdgcn_global_load_lds(                                 \
                (const __attribute__((address_space(1))) unsigned int*)      \
                    (xb + (long)garow[j] * 256 + k0_ + scol),                 \
                (__attribute__((address_space(3))) unsigned int*)             \
                    (&As[buf][(w * 4 + j) << 9]),                             \
                16, 0, 0);                                                    \
            __builtin_amdgcn_global_load_lds(                                 \
                (const __attribute__((address_space(1))) unsigned int*)      \
                    (wbt + (long)gbrow[j] * 256 + k0_ + scol),                \
                (__attribute__((address_space(3))) unsigned int*)             \
                    (&Bs[buf][(w * 4 + j) << 9]),                             \
                16, 0, 0);                                                    \
        }                                                                     \
    }

    f32x4 acc[4][4] = {};

    ISSUE(0, 0)
    for (int kk = 0; kk < 4; kk++) {
        const int buf = kk & 1;
        __syncthreads();                      // tile kk landed; prev reads of buf^1 done
        if (kk < 3) ISSUE(kk + 1, buf ^ 1)    // prefetch under compute
#pragma unroll
        for (int ks = 0; ks < 2; ks++) {
            const int cb = (ks * 64 + kg * 16) ^ ((lm & 7) << 4);
            short8 afr[4], bfr[4];
#pragma unroll
            for (int mi = 0; mi < 4; mi++) {
                int row = wr * 64 + mi * 16 + lm;
                afr[mi] = *(const short8*)((const char*)&As[buf][0] + row * 128 + cb);
            }
#pragma unroll
            for (int nj = 0; nj < 4; nj++) {
                int row = wc * 64 + nj * 16 + lm;
                bfr[nj] = *(const short8*)((const char*)&Bs[buf][0] + row * 128 + cb);
            }
#pragma unroll
            for (int mi = 0; mi < 4; mi++)
#pragma unroll
                for (int nj = 0; nj < 4; nj++)
                    acc[mi][nj] = __builtin_amdgcn_mfma_f32_16x16x32_bf16(
                        afr[mi], bfr[nj], acc[mi][nj], 0, 0, 0);
        }
    }
#undef ISSUE

    const bool isH = (bn0 < 256);
#pragma unroll
    for (int mi = 0; mi < 4; mi++) {
#pragma unroll
        for (int nj = 0; nj < 4; nj++) {
            int col = bn0 + wc * 64 + nj * 16 + lm;
            f32x4 a = acc[mi][nj];
            int rowbase = bm0 + wr * 64 + mi * 16 + kg * 4;
            if (isH) {
#pragma unroll
                for (int r = 0; r < 4; r++) {
                    int row = rowbase + r;
                    if (row < M) hb[(long)row * 256 + col] = f2bf(a[r]);
                }
            } else {
                int c2 = col - 256;
                float bft = b_ft[c2], mu = bn_m[c2];
                float iv = rsqrtf(bn_v[c2] + 1e-5f);
                float g = bn_g[c2], bt = bn_b[c2];
#pragma unroll
                for (int r = 0; r < 4; r++) {
                    int row = rowbase + r;
                    if (row < M) {
                        float v = (a[r] + bft - mu) * iv * g + bt;
                        v = v > 0.f ? v : 0.f;
                        if (tb) tb[(long)row * 256 + c2] = f2bf(v);
                        else    out[(long)row * 256 + c2] = v;
                    }
                }
            }
        }
    }

    // ---- attention coefficients (h blocks only): head = bn0/64 + wc ----
    if (isH) {
        const int head = (bn0 >> 6) + wc;
        float as_c[4], ad_c[4];
#pragma unroll
        for (int nj = 0; nj < 4; nj++) {
            as_c[nj] = att_s[head * 64 + nj * 16 + lm];
            ad_c[nj] = att_d[head * 64 + nj * 16 + lm];
        }
#pragma unroll
        for (int mi = 0; mi < 4; mi++) {
#pragma unroll
            for (int r = 0; r < 4; r++) {
                float s1 = 0.f, s2 = 0.f;
#pragma unroll
                for (int nj = 0; nj < 4; nj++) {
                    s1 = fmaf(acc[mi][nj][r], as_c[nj], s1);
                    s2 = fmaf(acc[mi][nj][r], ad_c[nj], s2);
                }
#pragma unroll
                for (int o = 1; o < 16; o <<= 1) {
                    s1 += __shfl_xor(s1, o);
                    s2 += __shfl_xor(s2, o);
                }
                int row = bm0 + wr * 64 + mi * 16 + kg * 4 + r;
                if (lm == 0 && row < M) {
                    a_src[(long)row * 4 + head] = s1;
                    a_dst[(long)row * 4 + head] = s2;
                }
            }
        }
    }
}

// ---------------- fallback GEMM (f32 x staging) — used only if ws can't fit xb ----
#define BK 32
__global__ __launch_bounds__(256) void k_gemm(
    const float* __restrict__ x, const unsigned short* __restrict__ wbt,
    unsigned short* __restrict__ hb, unsigned short* __restrict__ tb,
    float* __restrict__ out,
    const float* __restrict__ att_s, const float* __restrict__ att_d,
    float* __restrict__ a_src, float* __restrict__ a_dst,
    const float* __restrict__ b_ft, const float* __restrict__ bn_g,
    const float* __restrict__ bn_b, const float* __restrict__ bn_m,
    const float* __restrict__ bn_v, int M) {
    __shared__ unsigned short As[BM][BK + 8];
    __shared__ unsigned short Bs[BN][BK + 8];
    const int t = threadIdx.x;
    const int w = t >> 6, lane = t & 63;
    const int wr = w >> 1, wc = w & 1;
    const int bm0 = blockIdx.y * BM;
    const int bn0 = blockIdx.x * BN;
    const int kg = lane >> 4;
    const int lm = lane & 15;
    f32x4 acc[4][4] = {};
    for (int k0 = 0; k0 < 256; k0 += BK) {
        f32x4 a0[2], a1[2];
        usx8 bv[2];
#pragma unroll
        for (int s = 0; s < 2; s++) {
            int seg = t + s * 256;
            int row = seg >> 2;
            int off = (seg & 3) * 8;
            int grow = bm0 + row; if (grow >= M) grow = M - 1;
            const float* ap = x + (long)grow * 256 + k0 + off;
            a0[s] = *(const f32x4*)ap;
            a1[s] = *(const f32x4*)(ap + 4);
            bv[s] = *(const usx8*)(wbt + (long)(bn0 + row) * 256 + k0 + off);
        }
        __syncthreads();
#pragma unroll
        for (int s = 0; s < 2; s++) {
            int seg = t + s * 256;
            int row = seg >> 2;
            int off = (seg & 3) * 8;
            usx8 av;
            av[0] = f2bf(a0[s][0]); av[1] = f2bf(a0[s][1]);
            av[2] = f2bf(a0[s][2]); av[3] = f2bf(a0[s][3]);
            av[4] = f2bf(a1[s][0]); av[5] = f2bf(a1[s][1]);
            av[6] = f2bf(a1[s][2]); av[7] = f2bf(a1[s][3]);
            *(usx8*)&As[row][off] = av;
            *(usx8*)&Bs[row][off] = bv[s];
        }
        __syncthreads();
        short8 afr[4], bfr[4];
#pragma unroll
        for (int mi = 0; mi < 4; mi++)
            afr[mi] = *(const short8*)&As[wr * 64 + mi * 16 + lm][kg * 8];
#pragma unroll
        for (int nj = 0; nj < 4; nj++)
            bfr[nj] = *(const short8*)&Bs[wc * 64 + nj * 16 + lm][kg * 8];
#pragma unroll
        for (int mi = 0; mi < 4; mi++)
#pragma unroll
            for (int nj = 0; nj < 4; nj++)
                acc[mi][nj] = __builtin_amdgcn_mfma_f32_16x16x32_bf16(
                    afr[mi], bfr[nj], acc[mi][nj], 0, 0, 0);
        __syncthreads();
    }
    const bool isH = (bn0 < 256);
#pragma unroll
    for (int mi = 0; mi < 4; mi++) {
#pragma unroll
        for (int nj = 0; nj < 4; nj++) {
            int col = bn0 + wc * 64 + nj * 16 + lm;
            f32x4 a = acc[mi][nj];
            int rowbase = bm0 + wr * 64 + mi * 16 + kg * 4;
            if (isH) {
#pragma unroll
                for (int r = 0; r < 4; r++) {
                    int row = rowbase + r;
                    if (row < M) hb[(long)row * 256 + col] = f2bf(a[r]);
                }
            } else {
                int c2 = col - 256;
                float bft = b_ft[c2], mu = bn_m[c2];
                float iv = rsqrtf(bn_v[c2] + 1e-5f);
                float g = bn_g[c2], bt = bn_b[c2];
#pragma unroll
                for (int r = 0; r < 4; r++) {
                    int row = rowbase + r;
                    if (row < M) {
                        float v = (a[r] + bft - mu) * iv * g + bt;
                        v = v > 0.f ? v : 0.f;
                        if (tb) tb[(long)row * 256 + c2] = f2bf(v);
                        else    out[(long)row * 256 + c2] = v;
                    }
                }
            }
        }
    }
    if (isH) {
        const int head = (bn0 >> 6) + wc;
        float as_c[4], ad_c[4];
#pragma unroll
        for (int nj = 0; nj < 4; nj++) {
            as_c[nj] = att_s[head * 64 + nj * 16 + lm];
            ad_c[nj] = att_d[head * 64 + nj * 16 + lm];
        }
#pragma unroll
        for (int mi = 0; mi < 4; mi++) {
#pragma unroll
            for (int r = 0; r < 4; r++) {
                float s1 = 0.f, s2 = 0.f;
#pragma unroll
                for (int nj = 0; nj < 4; nj++) {
                    s1 = fmaf(acc[mi][nj][r], as_c[nj], s1);
                    s2 = fmaf(acc[mi][nj][r], ad_c[nj], s2);
                }
#pragma unroll
                for (int o = 1; o < 16; o <<= 1) {
                    s1 += __shfl_xor(s1, o);
                    s2 += __shfl_xor(s2, o);
                }
                int row = bm0 + wr * 64 + mi * 16 + kg * 4 + r;
                if (lm == 0 && row < M) {
                    a_src[(long)row * 4 + head] = s1;
                    a_dst[(long)row * 4 + head] = s2;
                }
            }
        }
    }
}

// ---------------- CSR build (edge_index is int32; self-loop at slot 0) ----------------
__global__ void k_count(const int* __restrict__ ei, int* __restrict__ deg, int E) {
    int i = blockIdx.x * blockDim.x + threadIdx.x;
    if (i < E) atomicAdd(&deg[ei[E + i]], 1);
}
__global__ __launch_bounds__(256) void k_scan1(const int* __restrict__ deg,
                                               int* __restrict__ offs,
                                               int* __restrict__ bsum, int n) {
    __shared__ int tmp[256];
    int b = blockIdx.x, t = threadIdx.x;
    int base = b * 1024;
    int v[4];
#pragma unroll
    for (int j = 0; j < 4; j++) {
        int i = base + t * 4 + j;
        v[j] = (i < n) ? (deg[i] + 1) : 0;     // +1 = self-loop
    }
    int local = v[0] + v[1] + v[2] + v[3];
    tmp[t] = local;
    __syncthreads();
    for (int off = 1; off < 256; off <<= 1) {
        int xv = (t >= off) ? tmp[t - off] : 0;
        __syncthreads();
        tmp[t] += xv;
        __syncthreads();
    }
    int run = tmp[t] - local;
    if (t == 255) bsum[b] = tmp[255];
#pragma unroll
    for (int j = 0; j < 4; j++) {
        int i = base + t * 4 + j;
        if (i < n) offs[i] = run;
        run += v[j];
    }
}
// finalize offsets (adds prefix of bsum on the fly) AND write the self-loop
__global__ void k_scan3f(int* __restrict__ offs, const int* __restrict__ bsum,
                         int* __restrict__ srcs, int n) {
    int i = blockIdx.x * blockDim.x + threadIdx.x;
    if (i >= n) return;
    int nbi = i >> 10;
    int s = 0;
    for (int j = 0; j < nbi; j++) s += bsum[j];   // <=48 L2-hit adds
    int o = offs[i] + s;
    offs[i] = o;
    srcs[o] = i;       // self-loop occupies slot 0
}
__global__ void k_scatter(const int* __restrict__ ei, const int* __restrict__ offs,
                          int* __restrict__ cursor, int* __restrict__ srcs, int E) {
    int i = blockIdx.x * blockDim.x + threadIdx.x;
    if (i >= E) return;
    int d = ei[E + i];
    int pos = atomicAdd(&cursor[d], 1);
    srcs[offs[d] + 1 + pos] = ei[i];
}

// ---------------- softmax + aggregation: ONE WAVE per destination node ----------------
__global__ __launch_bounds__(256, 4) void k_agg(
    const int* __restrict__ offs, const int* __restrict__ srcs,
    const unsigned short* __restrict__ hb,
    const float* __restrict__ a_src, const float* __restrict__ a_dst,
    const float* __restrict__ bias_gat, const unsigned short* __restrict__ tb,
    float* __restrict__ out, int N, int E) {
    const int n = (blockIdx.x * 256 + threadIdx.x) >> 6;   // node = global wave id
    const int l = threadIdx.x & 63;
    if (n >= N) return;
    const int head = l >> 4;
    const int sub = l & 15;
    const int beg = offs[n];
    const int end = (n + 1 < N) ? offs[n + 1] : (E + N);
    const uint2* hp = (const uint2*)hb + l;                // lane-constant base

    const float ad = a_dst[(long)n * 4 + head];
    f32x4 acc = {};
    float den = 0.f;

    for (int base = beg; base < end; base += 16) {
        const int len = min(16, end - base);
        int sv = 0;
        float wsel = 0.f;
        if (base + sub < end) {
            sv = srcs[base + sub];
            float lv = a_src[(long)sv * 4 + head] + ad;
            lv = fmaxf(lv, 0.2f * lv);            // LeakyReLU(0.2)
            wsel = __expf(lv);
        }

#define AGG_EDGE(i)                                                        \
        {                                                                  \
            int src = __shfl(sv, (i));                                     \
            float wgt = __shfl(wsel, (l & 48) + (i));                      \
            uint2 hv = hp[src << 6];                                       \
            den += wgt;                                                    \
            acc[0] = fmaf(wgt, __uint_as_float(hv.x << 16), acc[0]);       \
            acc[1] = fmaf(wgt, __uint_as_float(hv.x & 0xFFFF0000u), acc[1]);\
            acc[2] = fmaf(wgt, __uint_as_float(hv.y << 16), acc[2]);       \
            acc[3] = fmaf(wgt, __uint_as_float(hv.y & 0xFFFF0000u), acc[3]);\
        }

        if (len == 16) {
#pragma unroll
            for (int i = 0; i < 16; ++i) AGG_EDGE(i)
        } else {
            for (int i = 0; i < len; ++i) AGG_EDGE(i)
        }
#undef AGG_EDGE
    }

    const float inv = 1.f / (den + 1e-16f);
    const float4 bv = ((const float4*)bias_gat)[l];
    float4 trf;
    const long rowoff = ((long)n << 8) + l * 4;
    if (tb) {
        uint2 tv = ((const uint2*)(tb + ((long)n << 8)))[l];
        trf.x = __uint_as_float(tv.x << 16);
        trf.y = __uint_as_float(tv.x & 0xFFFF0000u);
        trf.z = __uint_as_float(tv.y << 16);
        trf.w = __uint_as_float(tv.y & 0xFFFF0000u);
    } else {
        trf = *(const float4*)(out + rowoff);
    }
    float4 r;
    r.x = acc[0] * inv + bv.x + trf.x;
    r.y = acc[1] * inv + bv.y + trf.y;
    r.z = acc[2] * inv + bv.z + trf.z;
    r.w = acc[3] * inv + bv.w + trf.w;
    *(float4*)(out + rowoff) = r;
}

extern "C" void kernel_launch(void* const* d_in, const int* in_sizes, int n_in,
                              void* d_out, int out_size, void* d_ws, size_t ws_size,
                              hipStream_t stream) {
    const float* x        = (const float*)d_in[0];
    const int*   ei       = (const int*)d_in[1];     // harness delivers integers as int32
    const float* W_gat    = (const float*)d_in[4];
    const float* att_src  = (const float*)d_in[5];
    const float* att_dst  = (const float*)d_in[6];
    const float* bias_gat = (const float*)d_in[7];
    const float* w_ft     = (const float*)d_in[12];
    const float* b_ft     = (const float*)d_in[13];
    const float* bn_g     = (const float*)d_in[14];
    const float* bn_b     = (const float*)d_in[15];
    const float* bn_m     = (const float*)d_in[16];
    const float* bn_v     = (const float*)d_in[17];
    float* out = (float*)d_out;

    const int N = in_sizes[0] / 256;
    const int E = in_sizes[1] / 2;
    const int ETOT = E + N;

    char* p = (char*)d_ws;
    char* pend = p + ws_size;
    auto alloc = [&](size_t bytes) {
        void* r = (void*)p;
        p += (bytes + 255) & ~(size_t)255;
        return r;
    };
    unsigned short* wbt  = (unsigned short*)alloc((size_t)512 * 256 * 2);
    unsigned short* hb   = (unsigned short*)alloc((size_t)N * 256 * 2);
    float* a_src = (float*)alloc((size_t)N * 4 * 4);
    float* a_dst = (float*)alloc((size_t)N * 4 * 4);
    char* z0 = p;                                    // zero region start
    int* deg    = (int*)alloc((size_t)N * 4);
    int* cursor = (int*)alloc((size_t)N * 4);
    char* z1 = p;                                    // zero region end
    int* offs   = (int*)alloc((size_t)(N + 1) * 4);
    int* bsum   = (int*)alloc((size_t)256 * 4);
    int* srcs   = (int*)alloc((size_t)ETOT * 4);
    unsigned short* xb = (unsigned short*)alloc((size_t)N * 256 * 2);
    if (p > pend) xb = nullptr;   // fall back to f32-staging GEMM
    unsigned short* tb = (unsigned short*)alloc((size_t)N * 256 * 2);
    if (p > pend) tb = nullptr;   // fall back to f32 path via d_out

    // fused prep: zero deg/cursor + build wbt + convert x
    const int zn = (int)((z1 - z0) / 4);
    const int nz = (zn + 255) / 256;
    const long total8 = (long)N * 256 / 8;
    const int nx = xb ? (int)((total8 + 255) / 256) : 0;
    k_prep<<<nz + 512 + nx, 256, 0, stream>>>((int*)z0, zn, W_gat, w_ft, wbt,
                                              x, xb, total8, nz);

    dim3 gg(4, (N + BM - 1) / BM);    // x = colblock fastest: A-panel L2 reuse
    if (xb) {
        k_gemm_fast<<<gg, 256, 0, stream>>>(xb, wbt, hb, tb, out, att_src, att_dst,
                                            a_src, a_dst, b_ft, bn_g, bn_b, bn_m, bn_v, N);
    } else {
        k_gemm<<<gg, 256, 0, stream>>>(x, wbt, hb, tb, out, att_src, att_dst,
                                       a_src, a_dst, b_ft, bn_g, bn_b, bn_m, bn_v, N);
    }

    k_count<<<(E + 255) / 256, 256, 0, stream>>>(ei, deg, E);
    int nb = (N + 1023) / 1024;
    k_scan1<<<nb, 256, 0, stream>>>(deg, offs, bsum, N);
    k_scan3f<<<(N + 255) / 256, 256, 0, stream>>>(offs, bsum, srcs, N);
    k_scatter<<<(E + 255) / 256, 256, 0, stream>>>(ei, offs, cursor, srcs, E);

    k_agg<<<(N * 64 + 255) / 256, 256, 0, stream>>>(offs, srcs, hb, a_src, a_dst,
                                                    bias_gat, tb, out, N, E);
}

// Round 15
// 224.821 us; speedup vs baseline: 1.0970x; 1.0970x over previous
//
#include <hip/hip_runtime.h>
#include <math.h>

typedef __attribute__((ext_vector_type(4))) float  f32x4;
typedef __attribute__((ext_vector_type(8))) short  short8;
typedef __attribute__((ext_vector_type(8))) unsigned short usx8;

__device__ __forceinline__ unsigned short f2bf(float f) {
    union { float f; unsigned int i; } c; c.f = f;
    unsigned int x = c.i;
    unsigned int r = (x + 0x7FFFu + ((x >> 16) & 1u)) >> 16;  // round-nearest-even
    return (unsigned short)r;
}

// ---------------- fused prep: zero CSR counters + convert W + convert x ----------------
__global__ __launch_bounds__(256) void k_prep(
    int* __restrict__ zr, int zn,
    const float* __restrict__ Wg, const float* __restrict__ Wf,
    unsigned short* __restrict__ wbt,
    const float* __restrict__ x, unsigned short* __restrict__ xb,
    long total8, int nz) {
    int b = blockIdx.x;
    if (b < nz) {
        int i = b * 256 + threadIdx.x;
        if (i < zn) zr[i] = 0;
        return;
    }
    b -= nz;
    if (b < 512) {
        int idx = b * 256 + threadIdx.x;
        int c = idx >> 8;
        int k = idx & 255;
        float v = (c < 256) ? Wg[k * 256 + c] : Wf[k * 256 + (c - 256)];
        wbt[idx] = f2bf(v);
        return;
    }
    b -= 512;
    long i = (long)b * 256 + threadIdx.x;
    if (i >= total8 || !xb) return;
    const f32x4* p = (const f32x4*)x;
    f32x4 v0 = p[2 * i], v1 = p[2 * i + 1];
    usx8 o;
    o[0] = f2bf(v0[0]); o[1] = f2bf(v0[1]); o[2] = f2bf(v0[2]); o[3] = f2bf(v0[3]);
    o[4] = f2bf(v1[0]); o[5] = f2bf(v1[1]); o[6] = f2bf(v1[2]); o[7] = f2bf(v1[3]);
    ((usx8*)xb)[i] = o;
}

#define BM 128
#define BN 128

// ---------------- fast GEMM: global_load_lds + BK=64 + XOR-swizzled LDS ----------------
// (round-13 single-buffered version: 32 KB LDS, 4 waves/SIMD)
__global__ __launch_bounds__(256, 4) void k_gemm_fast(
    const unsigned short* __restrict__ xb,    // [M][256] bf16
    const unsigned short* __restrict__ wbt,   // [512][256] bf16
    unsigned short* __restrict__ hb,          // [M][256] bf16 (GAT h)
    unsigned short* __restrict__ tb,          // [M][256] bf16 transformed (or null)
    float* __restrict__ out,                  // fallback f32 transformed target
    const float* __restrict__ att_s, const float* __restrict__ att_d,
    float* __restrict__ a_src, float* __restrict__ a_dst,
    const float* __restrict__ b_ft, const float* __restrict__ bn_g,
    const float* __restrict__ bn_b, const float* __restrict__ bn_m,
    const float* __restrict__ bn_v, int M) {
    __shared__ unsigned short As[128 * 64];   // 16 KB, swizzled storage
    __shared__ unsigned short Bs[128 * 64];   // 16 KB
    const int t = threadIdx.x;
    const int w = t >> 6, l = t & 63;
    const int wr = w >> 1, wc = w & 1;
    const int bm0 = blockIdx.y * BM;
    const int bn0 = blockIdx.x * BN;          // 0,128 -> h; 256,384 -> transformed
    const int kg = l >> 4;
    const int lm = l & 15;

    const int srow = l >> 3;                  // 0..7 within 8-row stripe
    const int scol = ((l & 7) ^ srow) << 3;   // pre-swizzled source col (bf16 units)

    f32x4 acc[4][4] = {};

    for (int kk = 0; kk < 4; kk++) {
        const int k0 = kk * 64;
        __syncthreads();                      // previous step's reads done
#pragma unroll
        for (int j = 0; j < 4; j++) {
            int r = ((w * 4 + j) << 3) + srow;           // 0..127
            int ga = bm0 + r; if (ga >= M) ga = M - 1;
            __builtin_amdgcn_global_load_lds(
                (const __attribute__((address_space(1))) unsigned int*)
                    (xb + (long)ga * 256 + k0 + scol),
                (__attribute__((address_space(3))) unsigned int*)
                    (As + ((w * 4 + j) << 9)),
                16, 0, 0);
            __builtin_amdgcn_global_load_lds(
                (const __attribute__((address_space(1))) unsigned int*)
                    (wbt + (long)(bn0 + r) * 256 + k0 + scol),
                (__attribute__((address_space(3))) unsigned int*)
                    (Bs + ((w * 4 + j) << 9)),
                16, 0, 0);
        }
        __syncthreads();                      // drains vmcnt before use
#pragma unroll
        for (int ks = 0; ks < 2; ks++) {
            const int cb = (ks * 64 + kg * 16) ^ ((lm & 7) << 4);
            short8 afr[4], bfr[4];
#pragma unroll
            for (int mi = 0; mi < 4; mi++) {
                int row = wr * 64 + mi * 16 + lm;
                afr[mi] = *(const short8*)((const char*)As + row * 128 + cb);
            }
#pragma unroll
            for (int nj = 0; nj < 4; nj++) {
                int row = wc * 64 + nj * 16 + lm;
                bfr[nj] = *(const short8*)((const char*)Bs + row * 128 + cb);
            }
#pragma unroll
            for (int mi = 0; mi < 4; mi++)
#pragma unroll
                for (int nj = 0; nj < 4; nj++)
                    acc[mi][nj] = __builtin_amdgcn_mfma_f32_16x16x32_bf16(
                        afr[mi], bfr[nj], acc[mi][nj], 0, 0, 0);
        }
    }

    const bool isH = (bn0 < 256);
#pragma unroll
    for (int mi = 0; mi < 4; mi++) {
#pragma unroll
        for (int nj = 0; nj < 4; nj++) {
            int col = bn0 + wc * 64 + nj * 16 + lm;
            f32x4 a = acc[mi][nj];
            int rowbase = bm0 + wr * 64 + mi * 16 + kg * 4;
            if (isH) {
#pragma unroll
                for (int r = 0; r < 4; r++) {
                    int row = rowbase + r;
                    if (row < M) hb[(long)row * 256 + col] = f2bf(a[r]);
                }
            } else {
                int c2 = col - 256;
                float bft = b_ft[c2], mu = bn_m[c2];
                float iv = rsqrtf(bn_v[c2] + 1e-5f);
                float g = bn_g[c2], bt = bn_b[c2];
#pragma unroll
                for (int r = 0; r < 4; r++) {
                    int row = rowbase + r;
                    if (row < M) {
                        float v = (a[r] + bft - mu) * iv * g + bt;
                        v = v > 0.f ? v : 0.f;
                        if (tb) tb[(long)row * 256 + c2] = f2bf(v);
                        else    out[(long)row * 256 + c2] = v;
                    }
                }
            }
        }
    }

    // ---- attention coefficients (h blocks only): head = bn0/64 + wc ----
    if (isH) {
        const int head = (bn0 >> 6) + wc;
        float as_c[4], ad_c[4];
#pragma unroll
        for (int nj = 0; nj < 4; nj++) {
            as_c[nj] = att_s[head * 64 + nj * 16 + lm];
            ad_c[nj] = att_d[head * 64 + nj * 16 + lm];
        }
#pragma unroll
        for (int mi = 0; mi < 4; mi++) {
#pragma unroll
            for (int r = 0; r < 4; r++) {
                float s1 = 0.f, s2 = 0.f;
#pragma unroll
                for (int nj = 0; nj < 4; nj++) {
                    s1 = fmaf(acc[mi][nj][r], as_c[nj], s1);
                    s2 = fmaf(acc[mi][nj][r], ad_c[nj], s2);
                }
#pragma unroll
                for (int o = 1; o < 16; o <<= 1) {
                    s1 += __shfl_xor(s1, o);
                    s2 += __shfl_xor(s2, o);
                }
                int row = bm0 + wr * 64 + mi * 16 + kg * 4 + r;
                if (lm == 0 && row < M) {
                    a_src[(long)row * 4 + head] = s1;
                    a_dst[(long)row * 4 + head] = s2;
                }
            }
        }
    }
}

// ---------------- fallback GEMM (f32 x staging) — used only if ws can't fit xb ----
#define BK 32
__global__ __launch_bounds__(256) void k_gemm(
    const float* __restrict__ x, const unsigned short* __restrict__ wbt,
    unsigned short* __restrict__ hb, unsigned short* __restrict__ tb,
    float* __restrict__ out,
    const float* __restrict__ att_s, const float* __restrict__ att_d,
    float* __restrict__ a_src, float* __restrict__ a_dst,
    const float* __restrict__ b_ft, const float* __restrict__ bn_g,
    const float* __restrict__ bn_b, const float* __restrict__ bn_m,
    const float* __restrict__ bn_v, int M) {
    __shared__ unsigned short As[BM][BK + 8];
    __shared__ unsigned short Bs[BN][BK + 8];
    const int t = threadIdx.x;
    const int w = t >> 6, lane = t & 63;
    const int wr = w >> 1, wc = w & 1;
    const int bm0 = blockIdx.y * BM;
    const int bn0 = blockIdx.x * BN;
    const int kg = lane >> 4;
    const int lm = lane & 15;
    f32x4 acc[4][4] = {};
    for (int k0 = 0; k0 < 256; k0 += BK) {
        f32x4 a0[2], a1[2];
        usx8 bv[2];
#pragma unroll
        for (int s = 0; s < 2; s++) {
            int seg = t + s * 256;
            int row = seg >> 2;
            int off = (seg & 3) * 8;
            int grow = bm0 + row; if (grow >= M) grow = M - 1;
            const float* ap = x + (long)grow * 256 + k0 + off;
            a0[s] = *(const f32x4*)ap;
            a1[s] = *(const f32x4*)(ap + 4);
            bv[s] = *(const usx8*)(wbt + (long)(bn0 + row) * 256 + k0 + off);
        }
        __syncthreads();
#pragma unroll
        for (int s = 0; s < 2; s++) {
            int seg = t + s * 256;
            int row = seg >> 2;
            int off = (seg & 3) * 8;
            usx8 av;
            av[0] = f2bf(a0[s][0]); av[1] = f2bf(a0[s][1]);
            av[2] = f2bf(a0[s][2]); av[3] = f2bf(a0[s][3]);
            av[4] = f2bf(a1[s][0]); av[5] = f2bf(a1[s][1]);
            av[6] = f2bf(a1[s][2]); av[7] = f2bf(a1[s][3]);
            *(usx8*)&As[row][off] = av;
            *(usx8*)&Bs[row][off] = bv[s];
        }
        __syncthreads();
        short8 afr[4], bfr[4];
#pragma unroll
        for (int mi = 0; mi < 4; mi++)
            afr[mi] = *(const short8*)&As[wr * 64 + mi * 16 + lm][kg * 8];
#pragma unroll
        for (int nj = 0; nj < 4; nj++)
            bfr[nj] = *(const short8*)&Bs[wc * 64 + nj * 16 + lm][kg * 8];
#pragma unroll
        for (int mi = 0; mi < 4; mi++)
#pragma unroll
            for (int nj = 0; nj < 4; nj++)
                acc[mi][nj] = __builtin_amdgcn_mfma_f32_16x16x32_bf16(
                    afr[mi], bfr[nj], acc[mi][nj], 0, 0, 0);
        __syncthreads();
    }
    const bool isH = (bn0 < 256);
#pragma unroll
    for (int mi = 0; mi < 4; mi++) {
#pragma unroll
        for (int nj = 0; nj < 4; nj++) {
            int col = bn0 + wc * 64 + nj * 16 + lm;
            f32x4 a = acc[mi][nj];
            int rowbase = bm0 + wr * 64 + mi * 16 + kg * 4;
            if (isH) {
#pragma unroll
                for (int r = 0; r < 4; r++) {
                    int row = rowbase + r;
                    if (row < M) hb[(long)row * 256 + col] = f2bf(a[r]);
                }
            } else {
                int c2 = col - 256;
                float bft = b_ft[c2], mu = bn_m[c2];
                float iv = rsqrtf(bn_v[c2] + 1e-5f);
                float g = bn_g[c2], bt = bn_b[c2];
#pragma unroll
                for (int r = 0; r < 4; r++) {
                    int row = rowbase + r;
                    if (row < M) {
                        float v = (a[r] + bft - mu) * iv * g + bt;
                        v = v > 0.f ? v : 0.f;
                        if (tb) tb[(long)row * 256 + c2] = f2bf(v);
                        else    out[(long)row * 256 + c2] = v;
                    }
                }
            }
        }
    }
    if (isH) {
        const int head = (bn0 >> 6) + wc;
        float as_c[4], ad_c[4];
#pragma unroll
        for (int nj = 0; nj < 4; nj++) {
            as_c[nj] = att_s[head * 64 + nj * 16 + lm];
            ad_c[nj] = att_d[head * 64 + nj * 16 + lm];
        }
#pragma unroll
        for (int mi = 0; mi < 4; mi++) {
#pragma unroll
            for (int r = 0; r < 4; r++) {
                float s1 = 0.f, s2 = 0.f;
#pragma unroll
                for (int nj = 0; nj < 4; nj++) {
                    s1 = fmaf(acc[mi][nj][r], as_c[nj], s1);
                    s2 = fmaf(acc[mi][nj][r], ad_c[nj], s2);
                }
#pragma unroll
                for (int o = 1; o < 16; o <<= 1) {
                    s1 += __shfl_xor(s1, o);
                    s2 += __shfl_xor(s2, o);
                }
                int row = bm0 + wr * 64 + mi * 16 + kg * 4 + r;
                if (lm == 0 && row < M) {
                    a_src[(long)row * 4 + head] = s1;
                    a_dst[(long)row * 4 + head] = s2;
                }
            }
        }
    }
}

// ---------------- CSR build (edge_index is int32; self-loop at slot 0) ----------------
__global__ void k_count(const int* __restrict__ ei, int* __restrict__ deg, int E) {
    int i = blockIdx.x * blockDim.x + threadIdx.x;
    if (i < E) atomicAdd(&deg[ei[E + i]], 1);
}
__global__ __launch_bounds__(256) void k_scan1(const int* __restrict__ deg,
                                               int* __restrict__ offs,
                                               int* __restrict__ bsum, int n) {
    __shared__ int tmp[256];
    int b = blockIdx.x, t = threadIdx.x;
    int base = b * 1024;
    int v[4];
#pragma unroll
    for (int j = 0; j < 4; j++) {
        int i = base + t * 4 + j;
        v[j] = (i < n) ? (deg[i] + 1) : 0;     // +1 = self-loop
    }
    int local = v[0] + v[1] + v[2] + v[3];
    tmp[t] = local;
    __syncthreads();
    for (int off = 1; off < 256; off <<= 1) {
        int xv = (t >= off) ? tmp[t - off] : 0;
        __syncthreads();
        tmp[t] += xv;
        __syncthreads();
    }
    int run = tmp[t] - local;
    if (t == 255) bsum[b] = tmp[255];
#pragma unroll
    for (int j = 0; j < 4; j++) {
        int i = base + t * 4 + j;
        if (i < n) offs[i] = run;
        run += v[j];
    }
}
// finalize offsets (adds prefix of bsum on the fly) AND write the self-loop
__global__ void k_scan3f(int* __restrict__ offs, const int* __restrict__ bsum,
                         int* __restrict__ srcs, int n) {
    int i = blockIdx.x * blockDim.x + threadIdx.x;
    if (i >= n) return;
    int nbi = i >> 10;
    int s = 0;
    for (int j = 0; j < nbi; j++) s += bsum[j];   // <=48 L2-hit adds
    int o = offs[i] + s;
    offs[i] = o;
    srcs[o] = i;       // self-loop occupies slot 0
}
__global__ void k_scatter(const int* __restrict__ ei, const int* __restrict__ offs,
                          int* __restrict__ cursor, int* __restrict__ srcs, int E) {
    int i = blockIdx.x * blockDim.x + threadIdx.x;
    if (i >= E) return;
    int d = ei[E + i];
    int pos = atomicAdd(&cursor[d], 1);
    srcs[offs[d] + 1 + pos] = ei[i];
}

// ---------------- softmax + aggregation: ONE WAVE per destination node ----------------
// 16-edge batch with INLINE-ASM loads: 16 distinct "=v" outputs force the register
// allocator to keep 16 global_load_dwordx2 in flight; one vmcnt(0) + sched_barrier
// fence, then the FMA sweep. Per-edge cost drops from ~1 miss-latency to ~1/16th.
__global__ __launch_bounds__(256, 4) void k_agg(
    const int* __restrict__ offs, const int* __restrict__ srcs,
    const unsigned short* __restrict__ hb,
    const float* __restrict__ a_src, const float* __restrict__ a_dst,
    const float* __restrict__ bias_gat, const unsigned short* __restrict__ tb,
    float* __restrict__ out, int N, int E) {
    const int n = (blockIdx.x * 256 + threadIdx.x) >> 6;   // node = global wave id
    const int l = threadIdx.x & 63;
    if (n >= N) return;
    const int head = l >> 4;
    const int sub = l & 15;
    const int beg = offs[n];
    const int end = (n + 1 < N) ? offs[n + 1] : (E + N);
    const uint2* hp = (const uint2*)hb + l;                // lane-constant base

    const float ad = a_dst[(long)n * 4 + head];
    f32x4 acc = {};
    float den = 0.f;

    for (int base = beg; base < end; base += 16) {
        const int len = min(16, end - base);
        int sv = 0;
        float wsel = 0.f;
        if (base + sub < end) {
            sv = srcs[base + sub];
            float lv = a_src[(long)sv * 4 + head] + ad;
            lv = fmaxf(lv, 0.2f * lv);            // LeakyReLU(0.2)
            wsel = __expf(lv);
        }

        if (len == 16) {
            uint2 hv[16];
#pragma unroll
            for (int i = 0; i < 16; ++i) {
                int src = __shfl(sv, i);
                const uint2* ap = hp + ((long)src << 6);
                asm volatile("global_load_dwordx2 %0, %1, off"
                             : "=v"(hv[i]) : "v"(ap));
            }
            float wg[16];
#pragma unroll
            for (int i = 0; i < 16; ++i) wg[i] = __shfl(wsel, (l & 48) + i);
            asm volatile("s_waitcnt vmcnt(0)" ::: "memory");
            __builtin_amdgcn_sched_barrier(0);   // nothing crosses: data has landed
#pragma unroll
            for (int i = 0; i < 16; ++i) {
                den += wg[i];
                acc[0] = fmaf(wg[i], __uint_as_float(hv[i].x << 16), acc[0]);
                acc[1] = fmaf(wg[i], __uint_as_float(hv[i].x & 0xFFFF0000u), acc[1]);
                acc[2] = fmaf(wg[i], __uint_as_float(hv[i].y << 16), acc[2]);
                acc[3] = fmaf(wg[i], __uint_as_float(hv[i].y & 0xFFFF0000u), acc[3]);
            }
        } else {
            for (int i = 0; i < len; ++i) {
                int src = __shfl(sv, i);
                float wgt = __shfl(wsel, (l & 48) + i);
                uint2 hv = hp[(long)src << 6];
                den += wgt;
                acc[0] = fmaf(wgt, __uint_as_float(hv.x << 16), acc[0]);
                acc[1] = fmaf(wgt, __uint_as_float(hv.x & 0xFFFF0000u), acc[1]);
                acc[2] = fmaf(wgt, __uint_as_float(hv.y << 16), acc[2]);
                acc[3] = fmaf(wgt, __uint_as_float(hv.y & 0xFFFF0000u), acc[3]);
            }
        }
    }

    const float inv = 1.f / (den + 1e-16f);
    const float4 bv = ((const float4*)bias_gat)[l];
    float4 trf;
    const long rowoff = ((long)n << 8) + l * 4;
    if (tb) {
        uint2 tv = ((const uint2*)(tb + ((long)n << 8)))[l];
        trf.x = __uint_as_float(tv.x << 16);
        trf.y = __uint_as_float(tv.x & 0xFFFF0000u);
        trf.z = __uint_as_float(tv.y << 16);
        trf.w = __uint_as_float(tv.y & 0xFFFF0000u);
    } else {
        trf = *(const float4*)(out + rowoff);
    }
    float4 r;
    r.x = acc[0] * inv + bv.x + trf.x;
    r.y = acc[1] * inv + bv.y + trf.y;
    r.z = acc[2] * inv + bv.z + trf.z;
    r.w = acc[3] * inv + bv.w + trf.w;
    *(float4*)(out + rowoff) = r;
}

extern "C" void kernel_launch(void* const* d_in, const int* in_sizes, int n_in,
                              void* d_out, int out_size, void* d_ws, size_t ws_size,
                              hipStream_t stream) {
    const float* x        = (const float*)d_in[0];
    const int*   ei       = (const int*)d_in[1];     // harness delivers integers as int32
    const float* W_gat    = (const float*)d_in[4];
    const float* att_src  = (const float*)d_in[5];
    const float* att_dst  = (const float*)d_in[6];
    const float* bias_gat = (const float*)d_in[7];
    const float* w_ft     = (const float*)d_in[12];
    const float* b_ft     = (const float*)d_in[13];
    const float* bn_g     = (const float*)d_in[14];
    const float* bn_b     = (const float*)d_in[15];
    const float* bn_m     = (const float*)d_in[16];
    const float* bn_v     = (const float*)d_in[17];
    float* out = (float*)d_out;

    const int N = in_sizes[0] / 256;
    const int E = in_sizes[1] / 2;
    const int ETOT = E + N;

    char* p = (char*)d_ws;
    char* pend = p + ws_size;
    auto alloc = [&](size_t bytes) {
        void* r = (void*)p;
        p += (bytes + 255) & ~(size_t)255;
        return r;
    };
    unsigned short* wbt  = (unsigned short*)alloc((size_t)512 * 256 * 2);
    unsigned short* hb   = (unsigned short*)alloc((size_t)N * 256 * 2);
    float* a_src = (float*)alloc((size_t)N * 4 * 4);
    float* a_dst = (float*)alloc((size_t)N * 4 * 4);
    char* z0 = p;                                    // zero region start
    int* deg    = (int*)alloc((size_t)N * 4);
    int* cursor = (int*)alloc((size_t)N * 4);
    char* z1 = p;                                    // zero region end
    int* offs   = (int*)alloc((size_t)(N + 1) * 4);
    int* bsum   = (int*)alloc((size_t)256 * 4);
    int* srcs   = (int*)alloc((size_t)ETOT * 4);
    unsigned short* xb = (unsigned short*)alloc((size_t)N * 256 * 2);
    if (p > pend) xb = nullptr;   // fall back to f32-staging GEMM
    unsigned short* tb = (unsigned short*)alloc((size_t)N * 256 * 2);
    if (p > pend) tb = nullptr;   // fall back to f32 path via d_out

    // fused prep: zero deg/cursor + build wbt + convert x
    const int zn = (int)((z1 - z0) / 4);
    const int nz = (zn + 255) / 256;
    const long total8 = (long)N * 256 / 8;
    const int nx = xb ? (int)((total8 + 255) / 256) : 0;
    k_prep<<<nz + 512 + nx, 256, 0, stream>>>((int*)z0, zn, W_gat, w_ft, wbt,
                                              x, xb, total8, nz);

    dim3 gg(4, (N + BM - 1) / BM);    // x = colblock fastest: A-panel L2 reuse
    if (xb) {
        k_gemm_fast<<<gg, 256, 0, stream>>>(xb, wbt, hb, tb, out, att_src, att_dst,
                                            a_src, a_dst, b_ft, bn_g, bn_b, bn_m, bn_v, N);
    } else {
        k_gemm<<<gg, 256, 0, stream>>>(x, wbt, hb, tb, out, att_src, att_dst,
                                       a_src, a_dst, b_ft, bn_g, bn_b, bn_m, bn_v, N);
    }

    k_count<<<(E + 255) / 256, 256, 0, stream>>>(ei, deg, E);
    int nb = (N + 1023) / 1024;
    k_scan1<<<nb, 256, 0, stream>>>(deg, offs, bsum, N);
    k_scan3f<<<(N + 255) / 256, 256, 0, stream>>>(offs, bsum, srcs, N);
    k_scatter<<<(E + 255) / 256, 256, 0, stream>>>(ei, offs, cursor, srcs, E);

    k_agg<<<(N * 64 + 255) / 256, 256, 0, stream>>>(offs, srcs, hb, a_src, a_dst,
                                                    bias_gat, tb, out, N, E);
}

// Round 16
// 219.961 us; speedup vs baseline: 1.1212x; 1.0221x over previous
//
#include <hip/hip_runtime.h>
#include <math.h>

typedef __attribute__((ext_vector_type(4))) float  f32x4;
typedef __attribute__((ext_vector_type(8))) short  short8;
typedef __attribute__((ext_vector_type(8))) unsigned short usx8;

__device__ __forceinline__ unsigned short f2bf(float f) {
    union { float f; unsigned int i; } c; c.f = f;
    unsigned int x = c.i;
    unsigned int r = (x + 0x7FFFu + ((x >> 16) & 1u)) >> 16;  // round-nearest-even
    return (unsigned short)r;
}

// ---------------- L1: zero CSR counters + convert W ----------------
__global__ __launch_bounds__(256) void k_prep1(
    int* __restrict__ zr, int zn,
    const float* __restrict__ Wg, const float* __restrict__ Wf,
    unsigned short* __restrict__ wbt, int nz) {
    int b = blockIdx.x;
    if (b < nz) {
        int i = b * 256 + threadIdx.x;
        if (i < zn) zr[i] = 0;
        return;
    }
    b -= nz;
    int idx = b * 256 + threadIdx.x;
    int c = idx >> 8;
    int k = idx & 255;
    float v = (c < 256) ? Wg[k * 256 + c] : Wf[k * 256 + (c - 256)];
    wbt[idx] = f2bf(v);
}

// ---------------- L2: convert x (f32->bf16) || count degrees ----------------
__global__ __launch_bounds__(256) void k_prep2(
    const float* __restrict__ x, unsigned short* __restrict__ xb, long total8, int nx,
    const int* __restrict__ ei, int* __restrict__ deg, int E) {
    int b = blockIdx.x;
    if (b < nx) {
        long i = (long)b * 256 + threadIdx.x;
        if (i >= total8) return;
        const f32x4* p = (const f32x4*)x;
        f32x4 v0 = p[2 * i], v1 = p[2 * i + 1];
        usx8 o;
        o[0] = f2bf(v0[0]); o[1] = f2bf(v0[1]); o[2] = f2bf(v0[2]); o[3] = f2bf(v0[3]);
        o[4] = f2bf(v1[0]); o[5] = f2bf(v1[1]); o[6] = f2bf(v1[2]); o[7] = f2bf(v1[3]);
        ((usx8*)xb)[i] = o;
        return;
    }
    int i = (b - nx) * 256 + threadIdx.x;
    if (i < E) atomicAdd(&deg[ei[E + i]], 1);
}

#define BM 128
#define BN 128

// ------- L3: fast GEMM (global_load_lds + BK=64 + XOR-swizzle) || scan1 -------
__global__ __launch_bounds__(256, 4) void k_gemm_scan(
    const unsigned short* __restrict__ xb,    // [M][256] bf16
    const unsigned short* __restrict__ wbt,   // [512][256] bf16
    unsigned short* __restrict__ hb,          // [M][256] bf16 (GAT h)
    unsigned short* __restrict__ tb,          // [M][256] bf16 transformed (or null)
    float* __restrict__ out,                  // fallback f32 transformed target
    const float* __restrict__ att_s, const float* __restrict__ att_d,
    float* __restrict__ a_src, float* __restrict__ a_dst,
    const float* __restrict__ b_ft, const float* __restrict__ bn_g,
    const float* __restrict__ bn_b, const float* __restrict__ bn_m,
    const float* __restrict__ bn_v, int M, int ngemm,
    const int* __restrict__ deg, int* __restrict__ offs, int* __restrict__ bsum) {
    __shared__ unsigned short As[128 * 64];   // 16 KB, swizzled storage
    __shared__ unsigned short Bs[128 * 64];   // 16 KB
    __shared__ int tmp[256];

    if (blockIdx.x >= ngemm) {
        // ---------------- scan1 part ----------------
        int b = blockIdx.x - ngemm, t = threadIdx.x;
        int base = b * 1024;
        int v[4];
#pragma unroll
        for (int j = 0; j < 4; j++) {
            int i = base + t * 4 + j;
            v[j] = (i < M) ? (deg[i] + 1) : 0;     // +1 = self-loop
        }
        int local = v[0] + v[1] + v[2] + v[3];
        tmp[t] = local;
        __syncthreads();
        for (int off = 1; off < 256; off <<= 1) {
            int xv = (t >= off) ? tmp[t - off] : 0;
            __syncthreads();
            tmp[t] += xv;
            __syncthreads();
        }
        int run = tmp[t] - local;
        if (t == 255) bsum[b] = tmp[255];
#pragma unroll
        for (int j = 0; j < 4; j++) {
            int i = base + t * 4 + j;
            if (i < M) offs[i] = run;
            run += v[j];
        }
        return;
    }

    // ---------------- GEMM part ----------------
    const int t = threadIdx.x;
    const int w = t >> 6, l = t & 63;
    const int wr = w >> 1, wc = w & 1;
    const int bm0 = (blockIdx.x >> 2) * BM;
    const int bn0 = (blockIdx.x & 3) * BN;    // 0,128 -> h; 256,384 -> transformed
    const int kg = l >> 4;
    const int lm = l & 15;

    const int srow = l >> 3;                  // 0..7 within 8-row stripe
    const int scol = ((l & 7) ^ srow) << 3;   // pre-swizzled source col (bf16 units)

    f32x4 acc[4][4] = {};

    for (int kk = 0; kk < 4; kk++) {
        const int k0 = kk * 64;
        __syncthreads();                      // previous step's reads done
#pragma unroll
        for (int j = 0; j < 4; j++) {
            int r = ((w * 4 + j) << 3) + srow;           // 0..127
            int ga = bm0 + r; if (ga >= M) ga = M - 1;
            __builtin_amdgcn_global_load_lds(
                (const __attribute__((address_space(1))) unsigned int*)
                    (xb + (long)ga * 256 + k0 + scol),
                (__attribute__((address_space(3))) unsigned int*)
                    (As + ((w * 4 + j) << 9)),
                16, 0, 0);
            __builtin_amdgcn_global_load_lds(
                (const __attribute__((address_space(1))) unsigned int*)
                    (wbt + (long)(bn0 + r) * 256 + k0 + scol),
                (__attribute__((address_space(3))) unsigned int*)
                    (Bs + ((w * 4 + j) << 9)),
                16, 0, 0);
        }
        __syncthreads();                      // drains vmcnt before use
#pragma unroll
        for (int ks = 0; ks < 2; ks++) {
            const int cb = (ks * 64 + kg * 16) ^ ((lm & 7) << 4);
            short8 afr[4], bfr[4];
#pragma unroll
            for (int mi = 0; mi < 4; mi++) {
                int row = wr * 64 + mi * 16 + lm;
                afr[mi] = *(const short8*)((const char*)As + row * 128 + cb);
            }
#pragma unroll
            for (int nj = 0; nj < 4; nj++) {
                int row = wc * 64 + nj * 16 + lm;
                bfr[nj] = *(const short8*)((const char*)Bs + row * 128 + cb);
            }
#pragma unroll
            for (int mi = 0; mi < 4; mi++)
#pragma unroll
                for (int nj = 0; nj < 4; nj++)
                    acc[mi][nj] = __builtin_amdgcn_mfma_f32_16x16x32_bf16(
                        afr[mi], bfr[nj], acc[mi][nj], 0, 0, 0);
        }
    }

    const bool isH = (bn0 < 256);
#pragma unroll
    for (int mi = 0; mi < 4; mi++) {
#pragma unroll
        for (int nj = 0; nj < 4; nj++) {
            int col = bn0 + wc * 64 + nj * 16 + lm;
            f32x4 a = acc[mi][nj];
            int rowbase = bm0 + wr * 64 + mi * 16 + kg * 4;
            if (isH) {
#pragma unroll
                for (int r = 0; r < 4; r++) {
                    int row = rowbase + r;
                    if (row < M) hb[(long)row * 256 + col] = f2bf(a[r]);
                }
            } else {
                int c2 = col - 256;
                float bft = b_ft[c2], mu = bn_m[c2];
                float iv = rsqrtf(bn_v[c2] + 1e-5f);
                float g = bn_g[c2], bt = bn_b[c2];
#pragma unroll
                for (int r = 0; r < 4; r++) {
                    int row = rowbase + r;
                    if (row < M) {
                        float v = (a[r] + bft - mu) * iv * g + bt;
                        v = v > 0.f ? v : 0.f;
                        if (tb) tb[(long)row * 256 + c2] = f2bf(v);
                        else    out[(long)row * 256 + c2] = v;
                    }
                }
            }
        }
    }

    // ---- attention coefficients (h blocks only): head = bn0/64 + wc ----
    if (isH) {
        const int head = (bn0 >> 6) + wc;
        float as_c[4], ad_c[4];
#pragma unroll
        for (int nj = 0; nj < 4; nj++) {
            as_c[nj] = att_s[head * 64 + nj * 16 + lm];
            ad_c[nj] = att_d[head * 64 + nj * 16 + lm];
        }
#pragma unroll
        for (int mi = 0; mi < 4; mi++) {
#pragma unroll
            for (int r = 0; r < 4; r++) {
                float s1 = 0.f, s2 = 0.f;
#pragma unroll
                for (int nj = 0; nj < 4; nj++) {
                    s1 = fmaf(acc[mi][nj][r], as_c[nj], s1);
                    s2 = fmaf(acc[mi][nj][r], ad_c[nj], s2);
                }
#pragma unroll
                for (int o = 1; o < 16; o <<= 1) {
                    s1 += __shfl_xor(s1, o);
                    s2 += __shfl_xor(s2, o);
                }
                int row = bm0 + wr * 64 + mi * 16 + kg * 4 + r;
                if (lm == 0 && row < M) {
                    a_src[(long)row * 4 + head] = s1;
                    a_dst[(long)row * 4 + head] = s2;
                }
            }
        }
    }
}

// ---------------- fallback GEMM (f32 x staging) — used only if ws can't fit xb ----
#define BK 32
__global__ __launch_bounds__(256) void k_gemm(
    const float* __restrict__ x, const unsigned short* __restrict__ wbt,
    unsigned short* __restrict__ hb, unsigned short* __restrict__ tb,
    float* __restrict__ out,
    const float* __restrict__ att_s, const float* __restrict__ att_d,
    float* __restrict__ a_src, float* __restrict__ a_dst,
    const float* __restrict__ b_ft, const float* __restrict__ bn_g,
    const float* __restrict__ bn_b, const float* __restrict__ bn_m,
    const float* __restrict__ bn_v, int M) {
    __shared__ unsigned short As[BM][BK + 8];
    __shared__ unsigned short Bs[BN][BK + 8];
    const int t = threadIdx.x;
    const int w = t >> 6, lane = t & 63;
    const int wr = w >> 1, wc = w & 1;
    const int bm0 = blockIdx.y * BM;
    const int bn0 = blockIdx.x * BN;
    const int kg = lane >> 4;
    const int lm = lane & 15;
    f32x4 acc[4][4] = {};
    for (int k0 = 0; k0 < 256; k0 += BK) {
        f32x4 a0[2], a1[2];
        usx8 bv[2];
#pragma unroll
        for (int s = 0; s < 2; s++) {
            int seg = t + s * 256;
            int row = seg >> 2;
            int off = (seg & 3) * 8;
            int grow = bm0 + row; if (grow >= M) grow = M - 1;
            const float* ap = x + (long)grow * 256 + k0 + off;
            a0[s] = *(const f32x4*)ap;
            a1[s] = *(const f32x4*)(ap + 4);
            bv[s] = *(const usx8*)(wbt + (long)(bn0 + row) * 256 + k0 + off);
        }
        __syncthreads();
#pragma unroll
        for (int s = 0; s < 2; s++) {
            int seg = t + s * 256;
            int row = seg >> 2;
            int off = (seg & 3) * 8;
            usx8 av;
            av[0] = f2bf(a0[s][0]); av[1] = f2bf(a0[s][1]);
            av[2] = f2bf(a0[s][2]); av[3] = f2bf(a0[s][3]);
            av[4] = f2bf(a1[s][0]); av[5] = f2bf(a1[s][1]);
            av[6] = f2bf(a1[s][2]); av[7] = f2bf(a1[s][3]);
            *(usx8*)&As[row][off] = av;
            *(usx8*)&Bs[row][off] = bv[s];
        }
        __syncthreads();
        short8 afr[4], bfr[4];
#pragma unroll
        for (int mi = 0; mi < 4; mi++)
            afr[mi] = *(const short8*)&As[wr * 64 + mi * 16 + lm][kg * 8];
#pragma unroll
        for (int nj = 0; nj < 4; nj++)
            bfr[nj] = *(const short8*)&Bs[wc * 64 + nj * 16 + lm][kg * 8];
#pragma unroll
        for (int mi = 0; mi < 4; mi++)
#pragma unroll
            for (int nj = 0; nj < 4; nj++)
                acc[mi][nj] = __builtin_amdgcn_mfma_f32_16x16x32_bf16(
                    afr[mi], bfr[nj], acc[mi][nj], 0, 0, 0);
        __syncthreads();
    }
    const bool isH = (bn0 < 256);
#pragma unroll
    for (int mi = 0; mi < 4; mi++) {
#pragma unroll
        for (int nj = 0; nj < 4; nj++) {
            int col = bn0 + wc * 64 + nj * 16 + lm;
            f32x4 a = acc[mi][nj];
            int rowbase = bm0 + wr * 64 + mi * 16 + kg * 4;
            if (isH) {
#pragma unroll
                for (int r = 0; r < 4; r++) {
                    int row = rowbase + r;
                    if (row < M) hb[(long)row * 256 + col] = f2bf(a[r]);
                }
            } else {
                int c2 = col - 256;
                float bft = b_ft[c2], mu = bn_m[c2];
                float iv = rsqrtf(bn_v[c2] + 1e-5f);
                float g = bn_g[c2], bt = bn_b[c2];
#pragma unroll
                for (int r = 0; r < 4; r++) {
                    int row = rowbase + r;
                    if (row < M) {
                        float v = (a[r] + bft - mu) * iv * g + bt;
                        v = v > 0.f ? v : 0.f;
                        if (tb) tb[(long)row * 256 + c2] = f2bf(v);
                        else    out[(long)row * 256 + c2] = v;
                    }
                }
            }
        }
    }
    if (isH) {
        const int head = (bn0 >> 6) + wc;
        float as_c[4], ad_c[4];
#pragma unroll
        for (int nj = 0; nj < 4; nj++) {
            as_c[nj] = att_s[head * 64 + nj * 16 + lm];
            ad_c[nj] = att_d[head * 64 + nj * 16 + lm];
        }
#pragma unroll
        for (int mi = 0; mi < 4; mi++) {
#pragma unroll
            for (int r = 0; r < 4; r++) {
                float s1 = 0.f, s2 = 0.f;
#pragma unroll
                for (int nj = 0; nj < 4; nj++) {
                    s1 = fmaf(acc[mi][nj][r], as_c[nj], s1);
                    s2 = fmaf(acc[mi][nj][r], ad_c[nj], s2);
                }
#pragma unroll
                for (int o = 1; o < 16; o <<= 1) {
                    s1 += __shfl_xor(s1, o);
                    s2 += __shfl_xor(s2, o);
                }
                int row = bm0 + wr * 64 + mi * 16 + kg * 4 + r;
                if (lm == 0 && row < M) {
                    a_src[(long)row * 4 + head] = s1;
                    a_dst[(long)row * 4 + head] = s2;
                }
            }
        }
    }
}

// fallback scan1 (separate launch when xb is null)
__global__ __launch_bounds__(256) void k_scan1(const int* __restrict__ deg,
                                               int* __restrict__ offs,
                                               int* __restrict__ bsum, int n) {
    __shared__ int tmp[256];
    int b = blockIdx.x, t = threadIdx.x;
    int base = b * 1024;
    int v[4];
#pragma unroll
    for (int j = 0; j < 4; j++) {
        int i = base + t * 4 + j;
        v[j] = (i < n) ? (deg[i] + 1) : 0;
    }
    int local = v[0] + v[1] + v[2] + v[3];
    tmp[t] = local;
    __syncthreads();
    for (int off = 1; off < 256; off <<= 1) {
        int xv = (t >= off) ? tmp[t - off] : 0;
        __syncthreads();
        tmp[t] += xv;
        __syncthreads();
    }
    int run = tmp[t] - local;
    if (t == 255) bsum[b] = tmp[255];
#pragma unroll
    for (int j = 0; j < 4; j++) {
        int i = base + t * 4 + j;
        if (i < n) offs[i] = run;
        run += v[j];
    }
}

// finalize offsets (adds prefix of bsum on the fly) AND write the self-loop
__global__ void k_scan3f(int* __restrict__ offs, const int* __restrict__ bsum,
                         int* __restrict__ srcs, int n) {
    int i = blockIdx.x * blockDim.x + threadIdx.x;
    if (i >= n) return;
    int nbi = i >> 10;
    int s = 0;
    for (int j = 0; j < nbi; j++) s += bsum[j];   // <=48 L2-hit adds
    int o = offs[i] + s;
    offs[i] = o;
    srcs[o] = i;       // self-loop occupies slot 0
}
__global__ void k_scatter(const int* __restrict__ ei, const int* __restrict__ offs,
                          int* __restrict__ cursor, int* __restrict__ srcs, int E) {
    int i = blockIdx.x * blockDim.x + threadIdx.x;
    if (i >= E) return;
    int d = ei[E + i];
    int pos = atomicAdd(&cursor[d], 1);
    srcs[offs[d] + 1 + pos] = ei[i];
}

// ---------------- softmax + aggregation: ONE WAVE per destination node ----------------
__global__ __launch_bounds__(256, 4) void k_agg(
    const int* __restrict__ offs, const int* __restrict__ srcs,
    const unsigned short* __restrict__ hb,
    const float* __restrict__ a_src, const float* __restrict__ a_dst,
    const float* __restrict__ bias_gat, const unsigned short* __restrict__ tb,
    float* __restrict__ out, int N, int E) {
    const int n = (blockIdx.x * 256 + threadIdx.x) >> 6;   // node = global wave id
    const int l = threadIdx.x & 63;
    if (n >= N) return;
    const int head = l >> 4;
    const int sub = l & 15;
    const int beg = offs[n];
    const int end = (n + 1 < N) ? offs[n + 1] : (E + N);
    const uint2* hp = (const uint2*)hb + l;                // lane-constant base

    const float ad = a_dst[(long)n * 4 + head];
    f32x4 acc = {};
    float den = 0.f;

    for (int base = beg; base < end; base += 16) {
        const int len = min(16, end - base);
        int sv = 0;
        float wsel = 0.f;
        if (base + sub < end) {
            sv = srcs[base + sub];
            float lv = a_src[(long)sv * 4 + head] + ad;
            lv = fmaxf(lv, 0.2f * lv);            // LeakyReLU(0.2)
            wsel = __expf(lv);
        }

        if (len == 16) {
            uint2 hv[16];
#pragma unroll
            for (int i = 0; i < 16; ++i) {
                int src = __shfl(sv, i);
                const uint2* ap = hp + ((long)src << 6);
                asm volatile("global_load_dwordx2 %0, %1, off"
                             : "=v"(hv[i]) : "v"(ap));
            }
            float wg[16];
#pragma unroll
            for (int i = 0; i < 16; ++i) wg[i] = __shfl(wsel, (l & 48) + i);
            asm volatile("s_waitcnt vmcnt(0)" ::: "memory");
            __builtin_amdgcn_sched_barrier(0);   // nothing crosses: data has landed
#pragma unroll
            for (int i = 0; i < 16; ++i) {
                den += wg[i];
                acc[0] = fmaf(wg[i], __uint_as_float(hv[i].x << 16), acc[0]);
                acc[1] = fmaf(wg[i], __uint_as_float(hv[i].x & 0xFFFF0000u), acc[1]);
                acc[2] = fmaf(wg[i], __uint_as_float(hv[i].y << 16), acc[2]);
                acc[3] = fmaf(wg[i], __uint_as_float(hv[i].y & 0xFFFF0000u), acc[3]);
            }
        } else {
            for (int i = 0; i < len; ++i) {
                int src = __shfl(sv, i);
                float wgt = __shfl(wsel, (l & 48) + i);
                uint2 hv = hp[(long)src << 6];
                den += wgt;
                acc[0] = fmaf(wgt, __uint_as_float(hv.x << 16), acc[0]);
                acc[1] = fmaf(wgt, __uint_as_float(hv.x & 0xFFFF0000u), acc[1]);
                acc[2] = fmaf(wgt, __uint_as_float(hv.y << 16), acc[2]);
                acc[3] = fmaf(wgt, __uint_as_float(hv.y & 0xFFFF0000u), acc[3]);
            }
        }
    }

    const float inv = 1.f / (den + 1e-16f);
    const float4 bv = ((const float4*)bias_gat)[l];
    float4 trf;
    const long rowoff = ((long)n << 8) + l * 4;
    if (tb) {
        uint2 tv = ((const uint2*)(tb + ((long)n << 8)))[l];
        trf.x = __uint_as_float(tv.x << 16);
        trf.y = __uint_as_float(tv.x & 0xFFFF0000u);
        trf.z = __uint_as_float(tv.y << 16);
        trf.w = __uint_as_float(tv.y & 0xFFFF0000u);
    } else {
        trf = *(const float4*)(out + rowoff);
    }
    float4 r;
    r.x = acc[0] * inv + bv.x + trf.x;
    r.y = acc[1] * inv + bv.y + trf.y;
    r.z = acc[2] * inv + bv.z + trf.z;
    r.w = acc[3] * inv + bv.w + trf.w;
    *(float4*)(out + rowoff) = r;
}

extern "C" void kernel_launch(void* const* d_in, const int* in_sizes, int n_in,
                              void* d_out, int out_size, void* d_ws, size_t ws_size,
                              hipStream_t stream) {
    const float* x        = (const float*)d_in[0];
    const int*   ei       = (const int*)d_in[1];     // harness delivers integers as int32
    const float* W_gat    = (const float*)d_in[4];
    const float* att_src  = (const float*)d_in[5];
    const float* att_dst  = (const float*)d_in[6];
    const float* bias_gat = (const float*)d_in[7];
    const float* w_ft     = (const float*)d_in[12];
    const float* b_ft     = (const float*)d_in[13];
    const float* bn_g     = (const float*)d_in[14];
    const float* bn_b     = (const float*)d_in[15];
    const float* bn_m     = (const float*)d_in[16];
    const float* bn_v     = (const float*)d_in[17];
    float* out = (float*)d_out;

    const int N = in_sizes[0] / 256;
    const int E = in_sizes[1] / 2;
    const int ETOT = E + N;

    char* p = (char*)d_ws;
    char* pend = p + ws_size;
    auto alloc = [&](size_t bytes) {
        void* r = (void*)p;
        p += (bytes + 255) & ~(size_t)255;
        return r;
    };
    unsigned short* wbt  = (unsigned short*)alloc((size_t)512 * 256 * 2);
    unsigned short* hb   = (unsigned short*)alloc((size_t)N * 256 * 2);
    float* a_src = (float*)alloc((size_t)N * 4 * 4);
    float* a_dst = (float*)alloc((size_t)N * 4 * 4);
    char* z0 = p;                                    // zero region start
    int* deg    = (int*)alloc((size_t)N * 4);
    int* cursor = (int*)alloc((size_t)N * 4);
    char* z1 = p;                                    // zero region end
    int* offs   = (int*)alloc((size_t)(N + 1) * 4);
    int* bsum   = (int*)alloc((size_t)256 * 4);
    int* srcs   = (int*)alloc((size_t)ETOT * 4);
    unsigned short* xb = (unsigned short*)alloc((size_t)N * 256 * 2);
    if (p > pend) xb = nullptr;   // fall back to f32-staging GEMM
    unsigned short* tb = (unsigned short*)alloc((size_t)N * 256 * 2);
    if (p > pend) tb = nullptr;   // fall back to f32 path via d_out

    const int zn = (int)((z1 - z0) / 4);
    const int nz = (zn + 255) / 256;
    const long total8 = (long)N * 256 / 8;
    const int nx = xb ? (int)((total8 + 255) / 256) : 0;
    const int ce = (E + 255) / 256;
    const int nb = (N + 1023) / 1024;
    const int ngemm = 4 * ((N + BM - 1) / BM);

    // L1: zero deg/cursor + build wbt
    k_prep1<<<nz + 512, 256, 0, stream>>>((int*)z0, zn, W_gat, w_ft, wbt, nz);

    if (xb) {
        // L2: convert x || count degrees
        k_prep2<<<nx + ce, 256, 0, stream>>>(x, xb, total8, nx, ei, deg, E);
        // L3: GEMM || scan1
        k_gemm_scan<<<ngemm + nb, 256, 0, stream>>>(
            xb, wbt, hb, tb, out, att_src, att_dst, a_src, a_dst,
            b_ft, bn_g, bn_b, bn_m, bn_v, N, ngemm, deg, offs, bsum);
    } else {
        k_prep2<<<ce, 256, 0, stream>>>(x, nullptr, 0, 0, ei, deg, E);
        dim3 gg(4, (N + BM - 1) / BM);
        k_gemm<<<gg, 256, 0, stream>>>(x, wbt, hb, tb, out, att_src, att_dst,
                                       a_src, a_dst, b_ft, bn_g, bn_b, bn_m, bn_v, N);
        k_scan1<<<nb, 256, 0, stream>>>(deg, offs, bsum, N);
    }

    // L4/L5: finalize offsets + scatter
    k_scan3f<<<(N + 255) / 256, 256, 0, stream>>>(offs, bsum, srcs, N);
    k_scatter<<<ce, 256, 0, stream>>>(ei, offs, cursor, srcs, E);

    // L6: aggregate
    k_agg<<<(N * 64 + 255) / 256, 256, 0, stream>>>(offs, srcs, hb, a_src, a_dst,
                                                    bias_gat, tb, out, N, E);
}